// Round 1
// baseline (539.969 us; speedup 1.0000x reference)
//
#include <hip/hip_runtime.h>
#include <hip/hip_bf16.h>

// Involution (B=16,C=256,H=W=56,K=7,G=16,RR=4).
// Pipeline: K1 reduce-GEMM (+BN partial stats), K2 BN finalize, K3 fused
// span-GEMM + involution. All fp32 (no fp32 MFMA on CDNA4 -> vector ALU).
// ws usage: r[64][50176] + partials[196][128] + AB[128] ~= 13 MB.

namespace {
constexpr int Bn = 16, Cn = 256, Hn = 56, Wn = 56, Kn = 7, Gn = 16, CRn = 64;
constexpr int HWn = Hn * Wn;            // 3136
constexpr int NPIX = Bn * HWn;          // 50176
constexpr int NBLK1 = NPIX / 256;       // 196
constexpr float EPSc = 1e-5f;

constexpr size_t R_OFF = 0;                               // [64][NPIX]
constexpr size_t PART_OFF = (size_t)CRn * NPIX;           // [NBLK1][128]
constexpr size_t AB_OFF = PART_OFF + (size_t)NBLK1 * 128; // [128] (A then B)
} // namespace

// ---------------------------------------------------------------------------
// K1: r[o][p] = sum_c x[b,c,hw] * w1[o][c]   (b1 dropped: cancels in BN)
// Each thread: 2 pixels x 32 out-channels. w1 in LDS (wave-uniform broadcast
// float4 reads). Also emits per-block partial sum/sumsq per channel.
// ---------------------------------------------------------------------------
__global__ __launch_bounds__(256) void k1_reduce(
    const float* __restrict__ x, const float* __restrict__ w1,
    float* __restrict__ r_ws, float* __restrict__ part_ws)
{
    __shared__ float w1s[CRn * Cn];     // 64 KB, [o][c]
    __shared__ float wpart[4][32][2];

    const int t = threadIdx.x;
    #pragma unroll
    for (int i = 0; i < (CRn * Cn) / 256; ++i)
        w1s[i * 256 + t] = w1[i * 256 + t];
    __syncthreads();

    const int oh = t >> 7;                  // which 32-channel half
    const int pl = t & 127;
    const int p0 = blockIdx.x * 256 + pl;
    const int p1 = p0 + 128;
    const int b0 = p0 / HWn, hw0 = p0 - b0 * HWn;
    const int b1i = p1 / HWn, hw1 = p1 - b1i * HWn;
    const float* xa = x + (size_t)b0 * Cn * HWn + hw0;
    const float* xb = x + (size_t)b1i * Cn * HWn + hw1;

    float acc0[32], acc1[32];
    #pragma unroll
    for (int o = 0; o < 32; ++o) { acc0[o] = 0.f; acc1[o] = 0.f; }

    const float* wbase = &w1s[(oh * 32) * Cn];
    for (int c4 = 0; c4 < Cn / 4; ++c4) {
        const float xa0 = xa[(c4 * 4 + 0) * HWn];
        const float xa1 = xa[(c4 * 4 + 1) * HWn];
        const float xa2 = xa[(c4 * 4 + 2) * HWn];
        const float xa3 = xa[(c4 * 4 + 3) * HWn];
        const float xb0 = xb[(c4 * 4 + 0) * HWn];
        const float xb1 = xb[(c4 * 4 + 1) * HWn];
        const float xb2 = xb[(c4 * 4 + 2) * HWn];
        const float xb3 = xb[(c4 * 4 + 3) * HWn];
        #pragma unroll
        for (int o = 0; o < 32; ++o) {
            const float4 w = *reinterpret_cast<const float4*>(wbase + o * Cn + c4 * 4);
            acc0[o] += xa0 * w.x + xa1 * w.y + xa2 * w.z + xa3 * w.w;
            acc1[o] += xb0 * w.x + xb1 * w.y + xb2 * w.z + xb3 * w.w;
        }
    }

    // store r (coalesced: lanes = consecutive pixels)
    #pragma unroll
    for (int o = 0; o < 32; ++o) {
        r_ws[(size_t)(oh * 32 + o) * NPIX + p0] = acc0[o];
        r_ws[(size_t)(oh * 32 + o) * NPIX + p1] = acc1[o];
    }

    // per-wave reduce of sum / sumsq for each of this half's 32 channels
    const int wv = t >> 6;
    #pragma unroll
    for (int o = 0; o < 32; ++o) {
        float s = acc0[o] + acc1[o];
        float q = acc0[o] * acc0[o] + acc1[o] * acc1[o];
        #pragma unroll
        for (int m = 1; m <= 32; m <<= 1) {
            s += __shfl_xor(s, m, 64);
            q += __shfl_xor(q, m, 64);
        }
        if ((t & 63) == 0) { wpart[wv][o][0] = s; wpart[wv][o][1] = q; }
    }
    __syncthreads();
    if (t < 128) {                       // t = o*2 + stat
        const int o = t >> 1, si = t & 1;
        const int ohh = o >> 5, ol = o & 31;
        part_ws[(size_t)blockIdx.x * 128 + t] =
            wpart[ohh * 2 + 0][ol][si] + wpart[ohh * 2 + 1][ol][si];
    }
}

// ---------------------------------------------------------------------------
// K2: fold block partials -> per-channel BN scale A / shift B
// ---------------------------------------------------------------------------
__global__ __launch_bounds__(128) void k2_stats(
    const float* __restrict__ part, const float* __restrict__ gamma,
    const float* __restrict__ beta, float* __restrict__ ab)
{
    const int t = threadIdx.x;           // t = o*2 + stat
    float s = 0.f;
    for (int blk = 0; blk < NBLK1; ++blk) s += part[(size_t)blk * 128 + t];
    __shared__ float L[128];
    L[t] = s;
    __syncthreads();
    if (t < 64) {
        const float inv = 1.0f / (float)NPIX;
        const float mean = L[2 * t] * inv;
        const float var = L[2 * t + 1] * inv - mean * mean;
        const float A = gamma[t] * rsqrtf(var + EPSc);
        ab[t] = A;
        ab[64 + t] = beta[t] - mean * A;
    }
}

// ---------------------------------------------------------------------------
// K3: per 8x8 pixel tile: stage BN+ReLU(r) in LDS, then per group g:
//   ker[px][ij] = sum_cr r[px][cr] * w2[ij*G+g][cr] + b2  (4px x 4tap x 4cr blocking)
//   out[b, g*16+d, h, w] = sum_ij xpad[.., h+i-3, w+j-3] * ker[px][ij]
// ---------------------------------------------------------------------------
__global__ __launch_bounds__(256) void k3_fused(
    const float* __restrict__ x, const float* __restrict__ w2,
    const float* __restrict__ b2, const float* __restrict__ r_ws,
    const float* __restrict__ ab_ws, float* __restrict__ out)
{
    __shared__ float r_s[CRn][72];       // [cr][px], pad 72: 2-way max
    __shared__ float w2_s[CRn][56];      // [cr][ij], pad 56: conflict-free
    __shared__ float ker_s[49][72];      // [ij][px]
    __shared__ float xp_s[16][14][14];   // [d][yy][xx] halo tile
    __shared__ float ab_s[128];

    const int t = threadIdx.x;
    const int w0 = blockIdx.x * 8, h0 = blockIdx.y * 8, b = blockIdx.z;

    if (t < 128) ab_s[t] = ab_ws[t];
    __syncthreads();

    // stage r tile with BN+ReLU applied: 64 cr x 64 px
    #pragma unroll
    for (int i = 0; i < 16; ++i) {
        const int v = i * 256 + t;
        const int o = v >> 6, px = v & 63;
        const int py = px >> 3, xx = px & 7;
        float val = r_ws[(size_t)o * NPIX + b * HWn + (h0 + py) * Wn + w0 + xx];
        val = fmaxf(val * ab_s[o] + ab_s[64 + o], 0.f);
        r_s[o][px] = val;
    }

    const int p_ = t & 15, q_ = t >> 4;            // span: px-quad, tap-quad
    const int d_ = t & 15;                         // involution: channel in group
    const int wq = (t >> 4) & 1, py_ = t >> 5;     // involution: w-quad, row

    for (int g = 0; g < Gn; ++g) {
        __syncthreads();   // w2_s/xp_s (and r_s on first iter) safe to (re)load

        // w2 slice for this group: rows o = ij*16+g, 64 floats each (coalesced)
        #pragma unroll
        for (int i = 0; i < 13; ++i) {
            const int v = i * 256 + t;
            if (v < 49 * 64) {
                const int ij = v >> 6, cr = v & 63;
                w2_s[cr][ij] = w2[(size_t)(ij * Gn + g) * CRn + cr];
            }
        }
        // x halo tile for this group's 16 channels
        #pragma unroll
        for (int i = 0; i < 13; ++i) {
            const int v = i * 256 + t;
            if (v < 16 * 196) {
                const int dd = v / 196, rem = v - dd * 196;
                const int yy = rem / 14, xx = rem - yy * 14;
                const int hh = h0 + yy - 3, ww = w0 + xx - 3;
                float val = 0.f;
                if (hh >= 0 && hh < Hn && ww >= 0 && ww < Wn)
                    val = x[((size_t)(b * Cn + g * 16 + dd) * Hn + hh) * Wn + ww];
                xp_s[dd][yy][xx] = val;
            }
        }
        __syncthreads();

        // span GEMM: 16 px-quads x 13 tap-quads = 208 active threads
        if (t < 208) {
            float acc[4][4];             // [tap k][px m]
            #pragma unroll
            for (int k = 0; k < 4; ++k)
                #pragma unroll
                for (int m = 0; m < 4; ++m) acc[k][m] = 0.f;
            const int px0 = p_ * 4, ij0 = q_ * 4;
            for (int cr = 0; cr < CRn; cr += 4) {
                float4 rv[4], wv[4];
                #pragma unroll
                for (int c = 0; c < 4; ++c) {
                    rv[c] = *reinterpret_cast<const float4*>(&r_s[cr + c][px0]);
                    wv[c] = *reinterpret_cast<const float4*>(&w2_s[cr + c][ij0]);
                }
                #pragma unroll
                for (int c = 0; c < 4; ++c) {
                    const float rc[4] = {rv[c].x, rv[c].y, rv[c].z, rv[c].w};
                    const float wc[4] = {wv[c].x, wv[c].y, wv[c].z, wv[c].w};
                    #pragma unroll
                    for (int k = 0; k < 4; ++k)
                        #pragma unroll
                        for (int m = 0; m < 4; ++m)
                            acc[k][m] += rc[m] * wc[k];
                }
            }
            const int ntap = (ij0 <= 45) ? 4 : 1;   // last quad holds only ij=48
            for (int k = 0; k < ntap; ++k) {
                const float bb = b2[(ij0 + k) * Gn + g];
                const float4 o4 = make_float4(acc[k][0] + bb, acc[k][1] + bb,
                                              acc[k][2] + bb, acc[k][3] + bb);
                *reinterpret_cast<float4*>(&ker_s[ij0 + k][px0]) = o4;
            }
        }
        __syncthreads();

        // involution: thread -> (d, row py_, w-quad wq): 4 outputs
        {
            float o0 = 0.f, o1 = 0.f, o2 = 0.f, o3 = 0.f;
            #pragma unroll
            for (int i = 0; i < Kn; ++i) {
                float xr[10];
                #pragma unroll
                for (int u = 0; u < 10; ++u)
                    xr[u] = xp_s[d_][py_ + i][wq * 4 + u];
                #pragma unroll
                for (int j = 0; j < Kn; ++j) {
                    const float4 kv = *reinterpret_cast<const float4*>(
                        &ker_s[i * Kn + j][py_ * 8 + wq * 4]);
                    o0 += xr[j + 0] * kv.x;
                    o1 += xr[j + 1] * kv.y;
                    o2 += xr[j + 2] * kv.z;
                    o3 += xr[j + 3] * kv.w;
                }
            }
            const float4 ov = make_float4(o0, o1, o2, o3);
            *reinterpret_cast<float4*>(
                &out[((size_t)(b * Cn + g * 16 + d_) * Hn + h0 + py_) * Wn
                     + w0 + wq * 4]) = ov;
        }
    }
}

// ---------------------------------------------------------------------------
extern "C" void kernel_launch(void* const* d_in, const int* in_sizes, int n_in,
                              void* d_out, int out_size, void* d_ws, size_t ws_size,
                              hipStream_t stream)
{
    const float* x     = (const float*)d_in[0];
    const float* w1    = (const float*)d_in[1];
    // d_in[2] = b1: unused (pure channel shift, cancelled by training-mode BN)
    const float* gamma = (const float*)d_in[3];
    const float* beta  = (const float*)d_in[4];
    const float* w2    = (const float*)d_in[5];
    const float* b2    = (const float*)d_in[6];
    float* out = (float*)d_out;
    float* ws  = (float*)d_ws;

    float* r_ws    = ws + R_OFF;
    float* part_ws = ws + PART_OFF;
    float* ab_ws   = ws + AB_OFF;

    k1_reduce<<<NBLK1, 256, 0, stream>>>(x, w1, r_ws, part_ws);
    k2_stats<<<1, 128, 0, stream>>>(part_ws, gamma, beta, ab_ws);
    k3_fused<<<dim3(Wn / 8, Hn / 8, Bn), 256, 0, stream>>>(x, w2, b2, r_ws,
                                                           ab_ws, out);
}

// Round 2
// 425.710 us; speedup vs baseline: 1.2684x; 1.2684x over previous
//
#include <hip/hip_runtime.h>

// Involution (B=16,C=256,H=W=56,K=7,G=16,CR=64), fp32 (no fp32 MFMA on CDNA4).
// K0: transpose w1->w1t[c][o], w2->w2t[g][cr][56] (taps zero-padded 49->56)
// K1: reduce GEMM r[o][px] (x tile in LDS, w1t from L1) + per-block BN partials
// K2: fold partials -> per-channel scale A / shift B
// K2b: r = relu(A*r+B) in place
// K3: per (b,g,28x4 tile): register span-GEMM (r/w2t from L1/L2) -> ker_s,
//     single barrier, involution from xp_s + ker_s. LDS 46KB -> 3 blocks/CU.

namespace {
constexpr int Bn = 16, Cn = 256, Hn = 56, Wn = 56, Gn = 16, CRn = 64;
constexpr int HWn = Hn * Wn;          // 3136
constexpr int NPIX = Bn * HWn;        // 50176
constexpr int NBLK1 = NPIX / 64;      // 784 (3136 = 49*64, no image straddle)
constexpr float EPSc = 1e-5f;

constexpr size_t R_OFF    = 0;                                  // [64][NPIX]
constexpr size_t PART_OFF = (size_t)CRn * NPIX;                 // [784][128]
constexpr size_t AB_OFF   = PART_OFF + (size_t)NBLK1 * 128;     // [128]
constexpr size_t W1T_OFF  = AB_OFF + 128;                       // [256][64]
constexpr size_t W2T_OFF  = W1T_OFF + 256 * 64;                 // [16][64][56]
} // namespace

// ---------------------------------------------------------------------------
__global__ __launch_bounds__(256) void k0_transpose(
    const float* __restrict__ w1, const float* __restrict__ w2,
    float* __restrict__ w1t, float* __restrict__ w2t)
{
    const int i = blockIdx.x * 256 + threadIdx.x;
    if (i < 256 * 64) {                       // w1t[c][o] = w1[o][c]
        const int o = i & 63, c = i >> 6;
        w1t[i] = w1[o * Cn + c];
    }
    const int j = i - 256 * 64;
    if (j >= 0 && j < Gn * CRn * 56) {        // w2t[g][cr][ij], pad ij>=49 -> 0
        const int ij = j % 56; const int crg = j / 56;
        const int cr = crg & 63, g = crg >> 6;
        w2t[j] = (ij < 49) ? w2[(size_t)(ij * Gn + g) * CRn + cr] : 0.f;
    }
}

// ---------------------------------------------------------------------------
// K1: 784 blocks, 64-px tile, 64 out channels. Thread (pq,oq) = 4px x 4o.
// x chunk [64c][64px] in LDS; w1t rows from global (L1 broadcast).
// ---------------------------------------------------------------------------
__global__ __launch_bounds__(256, 4) void k1_reduce(
    const float* __restrict__ x, const float* __restrict__ w1t,
    float* __restrict__ r_ws, float* __restrict__ part_ws)
{
    __shared__ float xs[64][68];
    __shared__ float wpart[16][4][2];

    const int t = threadIdx.x;
    const int blk = blockIdx.x;
    const int b = blk / 49;
    const int hw0 = (blk - b * 49) * 64;
    const int pq = t & 15, oq = t >> 4;

    const int sp = t & 63;                    // staging column (fixed px)
    const int sr = t >> 6;                    // staging start row
    const float* xbase = x + (size_t)b * Cn * HWn + hw0 + sp;

    float acc[4][4];
    #pragma unroll
    for (int a = 0; a < 4; ++a)
        #pragma unroll
        for (int p = 0; p < 4; ++p) acc[a][p] = 0.f;

    for (int ch = 0; ch < 4; ++ch) {
        const int c0 = ch * 64;
        __syncthreads();
        #pragma unroll
        for (int k = 0; k < 16; ++k) {
            const int row = sr + k * 4;
            xs[row][sp] = xbase[(size_t)(c0 + row) * HWn];
        }
        __syncthreads();

        #pragma unroll 4
        for (int cq = 0; cq < 16; ++cq) {
            #pragma unroll
            for (int c = 0; c < 4; ++c) {
                const int cc = cq * 4 + c;
                const float4 xv = *reinterpret_cast<const float4*>(&xs[cc][pq * 4]);
                const float4 wv = *reinterpret_cast<const float4*>(
                    &w1t[(size_t)(c0 + cc) * 64 + oq * 4]);
                const float xf[4] = {xv.x, xv.y, xv.z, xv.w};
                const float wf[4] = {wv.x, wv.y, wv.z, wv.w};
                #pragma unroll
                for (int a = 0; a < 4; ++a)
                    #pragma unroll
                    for (int p = 0; p < 4; ++p)
                        acc[a][p] += wf[a] * xf[p];
            }
        }
    }

    // write r (raw)
    const int px0 = b * HWn + hw0 + pq * 4;
    #pragma unroll
    for (int a = 0; a < 4; ++a) {
        const float4 st = make_float4(acc[a][0], acc[a][1], acc[a][2], acc[a][3]);
        *reinterpret_cast<float4*>(&r_ws[(size_t)(oq * 4 + a) * NPIX + px0]) = st;
    }

    // BN partials: per-o sum / sumsq over this block's 64 px
    #pragma unroll
    for (int a = 0; a < 4; ++a) {
        float s = acc[a][0] + acc[a][1] + acc[a][2] + acc[a][3];
        float q = acc[a][0] * acc[a][0] + acc[a][1] * acc[a][1]
                + acc[a][2] * acc[a][2] + acc[a][3] * acc[a][3];
        #pragma unroll
        for (int m = 1; m <= 8; m <<= 1) {
            s += __shfl_xor(s, m, 64);
            q += __shfl_xor(q, m, 64);
        }
        if (pq == 0) { wpart[oq][a][0] = s; wpart[oq][a][1] = q; }
    }
    __syncthreads();
    if (t < 128) {                            // t = o*2 + stat
        const int o = t >> 1;
        part_ws[(size_t)blk * 128 + t] = wpart[o >> 2][o & 3][t & 1];
    }
}

// ---------------------------------------------------------------------------
__global__ __launch_bounds__(128) void k2_stats(
    const float* __restrict__ part, const float* __restrict__ gamma,
    const float* __restrict__ beta, float* __restrict__ ab)
{
    const int t = threadIdx.x;
    float s0 = 0.f, s1 = 0.f, s2 = 0.f, s3 = 0.f;
    for (int blk = 0; blk < NBLK1; blk += 4) {
        s0 += part[(size_t)(blk + 0) * 128 + t];
        s1 += part[(size_t)(blk + 1) * 128 + t];
        s2 += part[(size_t)(blk + 2) * 128 + t];
        s3 += part[(size_t)(blk + 3) * 128 + t];
    }
    __shared__ float L[128];
    L[t] = (s0 + s1) + (s2 + s3);
    __syncthreads();
    if (t < 64) {
        const float inv = 1.0f / (float)NPIX;
        const float mean = L[2 * t] * inv;
        const float var = L[2 * t + 1] * inv - mean * mean;
        const float A = gamma[t] * rsqrtf(var + EPSc);
        ab[t] = A;
        ab[64 + t] = beta[t] - mean * A;
    }
}

// ---------------------------------------------------------------------------
__global__ __launch_bounds__(256) void k2b_bnrelu(
    float* __restrict__ r, const float* __restrict__ ab)
{
    const int i = blockIdx.x * 256 + threadIdx.x;   // float4 index, 802816 total
    const int o = i / (NPIX / 4);
    float4 v = reinterpret_cast<float4*>(r)[i];
    const float A = ab[o], Bb = ab[64 + o];
    v.x = fmaxf(A * v.x + Bb, 0.f);
    v.y = fmaxf(A * v.y + Bb, 0.f);
    v.z = fmaxf(A * v.z + Bb, 0.f);
    v.w = fmaxf(A * v.w + Bb, 0.f);
    reinterpret_cast<float4*>(r)[i] = v;
}

// ---------------------------------------------------------------------------
// K3: grid (2,14,256) = (w-tile 28, h-tile 4, b*1+g*16). One (b,g) per block.
// Phase A: stage x halo [16][10][36]; register GEMM ker[56 taps][4px] per
// thread (r2 + w2t from L1/L2), write ker_s. ONE barrier. Phase B: involution.
// ---------------------------------------------------------------------------
__global__ __launch_bounds__(256, 3) void k3_fused(
    const float* __restrict__ x, const float* __restrict__ r2,
    const float* __restrict__ w2t, const float* __restrict__ b2,
    float* __restrict__ out)
{
    __shared__ float ker_s[49][116];          // 22.7 KB
    __shared__ float xp_s[16][10][36];        // 23.0 KB

    const int t = threadIdx.x;
    const int w0 = blockIdx.x * 28;
    const int h0 = blockIdx.y * 4;
    const int bz = blockIdx.z;
    const int b = bz & 15, g = bz >> 4;

    // ---- stage x halo (all threads); GEMM below doesn't touch LDS
    {
        const float* xg = x + (size_t)(b * Cn + g * 16) * HWn;
        for (int e = t; e < 16 * 10 * 34; e += 256) {
            const int d = e / 340;
            const int rem = e - d * 340;
            const int yy = rem / 34;
            const int xx = rem - yy * 34;
            const int hh = h0 + yy - 3, ww = w0 + xx - 3;
            float v = 0.f;
            if (hh >= 0 && hh < Hn && ww >= 0 && ww < Wn)
                v = xg[(size_t)d * HWn + hh * Wn + ww];
            xp_s[d][yy][xx] = v;
        }
    }

    // ---- span GEMM: thread (pq 0..27, tg 0..6) -> 4 px x 8 taps
    if (t < 196) {
        const int pq = t % 28, tg = t / 28;
        const int row = pq / 7, qx = pq % 7;
        const int px0 = b * HWn + (h0 + row) * Wn + w0 + qx * 4;
        const float* rp = r2 + px0;
        const float* wp = w2t + (size_t)g * 64 * 56 + tg * 8;

        float acc[8][4];
        #pragma unroll
        for (int k = 0; k < 8; ++k)
            #pragma unroll
            for (int p = 0; p < 4; ++p) acc[k][p] = 0.f;

        #pragma unroll 4
        for (int cr = 0; cr < 64; ++cr) {
            const float4 rv = *reinterpret_cast<const float4*>(rp + (size_t)cr * NPIX);
            const float4 wa = *reinterpret_cast<const float4*>(wp + cr * 56);
            const float4 wb = *reinterpret_cast<const float4*>(wp + cr * 56 + 4);
            const float rf[4] = {rv.x, rv.y, rv.z, rv.w};
            const float wf[8] = {wa.x, wa.y, wa.z, wa.w, wb.x, wb.y, wb.z, wb.w};
            #pragma unroll
            for (int k = 0; k < 8; ++k)
                #pragma unroll
                for (int p = 0; p < 4; ++p)
                    acc[k][p] += wf[k] * rf[p];
        }
        #pragma unroll
        for (int k = 0; k < 8; ++k) {
            const int ij = tg * 8 + k;
            if (ij < 49) {
                const float bb = b2[ij * Gn + g];
                const float4 o4 = make_float4(acc[k][0] + bb, acc[k][1] + bb,
                                              acc[k][2] + bb, acc[k][3] + bb);
                *reinterpret_cast<float4*>(&ker_s[ij][pq * 4]) = o4;
            }
        }
    }

    __syncthreads();   // the only barrier

    // ---- involution: thread (pq 0..27, dp 0..7) -> 4 px x 2 channels
    if (t < 224) {
        const int pq = t % 28, dp = t / 28;
        const int qy = pq / 7, qx = pq % 7;
        const int d0 = dp * 2;

        float o0[4] = {0.f, 0.f, 0.f, 0.f};
        float o1[4] = {0.f, 0.f, 0.f, 0.f};
        #pragma unroll
        for (int i = 0; i < 7; ++i) {
            float xr0[12], xr1[12];
            #pragma unroll
            for (int u = 0; u < 3; ++u) {
                *reinterpret_cast<float4*>(&xr0[u * 4]) =
                    *reinterpret_cast<const float4*>(&xp_s[d0][qy + i][qx * 4 + u * 4]);
                *reinterpret_cast<float4*>(&xr1[u * 4]) =
                    *reinterpret_cast<const float4*>(&xp_s[d0 + 1][qy + i][qx * 4 + u * 4]);
            }
            #pragma unroll
            for (int j = 0; j < 7; ++j) {
                const float4 kv = *reinterpret_cast<const float4*>(&ker_s[i * 7 + j][pq * 4]);
                const float kf[4] = {kv.x, kv.y, kv.z, kv.w};
                #pragma unroll
                for (int p = 0; p < 4; ++p) {
                    o0[p] += xr0[j + p] * kf[p];
                    o1[p] += xr1[j + p] * kf[p];
                }
            }
        }
        float* op = out + ((size_t)(b * Cn + g * 16 + d0) * Hn + h0 + qy) * Wn
                    + w0 + qx * 4;
        *reinterpret_cast<float4*>(op) = make_float4(o0[0], o0[1], o0[2], o0[3]);
        *reinterpret_cast<float4*>(op + HWn) = make_float4(o1[0], o1[1], o1[2], o1[3]);
    }
}

// ---------------------------------------------------------------------------
extern "C" void kernel_launch(void* const* d_in, const int* in_sizes, int n_in,
                              void* d_out, int out_size, void* d_ws, size_t ws_size,
                              hipStream_t stream)
{
    const float* x     = (const float*)d_in[0];
    const float* w1    = (const float*)d_in[1];
    // d_in[2] = b1: cancels exactly under training-mode BN
    const float* gamma = (const float*)d_in[3];
    const float* beta  = (const float*)d_in[4];
    const float* w2    = (const float*)d_in[5];
    const float* b2    = (const float*)d_in[6];
    float* out = (float*)d_out;
    float* ws  = (float*)d_ws;

    float* r_ws    = ws + R_OFF;     // raw r, BN+ReLU applied in place by k2b
    float* part_ws = ws + PART_OFF;
    float* ab_ws   = ws + AB_OFF;
    float* w1t     = ws + W1T_OFF;
    float* w2t     = ws + W2T_OFF;

    k0_transpose<<<(256 * 64 + Gn * CRn * 56 + 255) / 256, 256, 0, stream>>>(
        w1, w2, w1t, w2t);
    k1_reduce<<<NBLK1, 256, 0, stream>>>(x, w1t, r_ws, part_ws);
    k2_stats<<<1, 128, 0, stream>>>(part_ws, gamma, beta, ab_ws);
    k2b_bnrelu<<<(CRn * NPIX / 4) / 256, 256, 0, stream>>>(r_ws, ab_ws);
    k3_fused<<<dim3(2, 14, 256), 256, 0, stream>>>(x, r_ws, w2t, b2, out);
}

// Round 4
// 375.754 us; speedup vs baseline: 1.4370x; 1.1329x over previous
//
#include <hip/hip_runtime.h>

// Involution (B=16,C=256,H=W=56,K=7,G=16,CR=64).
// Both GEMMs on MFMA (mfma_f32_16x16x32_bf16) via split-bf16 3-term
// (hi*hi + hi*lo + lo*hi), fp32 accumulate. Involution stays fp32 VALU.
// Pipeline:
//   K0  : w1 -> bf16 hi/lo [o][c] (B-operand natural layout);
//         w2 -> bf16 hi/lo [g][tap(64,zero-pad)][cr]
//   K1  : MFMA reduce GEMM -> rT fp32 [NPIX][64] + BN partials
//         (x transposed+split on the fly in XOR-swizzled LDS)
//   K2  : fold partials -> per-channel BN scale/shift
//   K2b : rT -> relu(A*rT+B) -> bf16 hi/lo [NPIX][64]
//   K3  : per (b,g,28x4 px tile): MFMA span GEMM -> ker_s, one barrier,
//         fp32 involution (unchanged from verified R2 code)
// ws ~26 MB.

namespace {
constexpr int Bn = 16, Cn = 256, Hn = 56, Wn = 56, Gn = 16, CRn = 64;
constexpr int HWn = Hn * Wn;          // 3136
constexpr int NPIX = Bn * HWn;        // 50176
constexpr int K1B = NPIX / 128;       // 392 (flat px tiles; b-straddle handled)
constexpr float EPSc = 1e-5f;

// ws byte offsets (16B-aligned)
constexpr size_t RT_OFF   = 0;                               // fp32 [NPIX][64]
constexpr size_t RH_OFF   = RT_OFF + (size_t)NPIX * 64 * 4;  // u16 [NPIX][64]
constexpr size_t RL_OFF   = RH_OFF + (size_t)NPIX * 64 * 2;
constexpr size_t PART_OFF = RL_OFF + (size_t)NPIX * 64 * 2;  // fp32 [392][128]
constexpr size_t AB_OFF   = PART_OFF + (size_t)K1B * 128 * 4;
constexpr size_t W1H_OFF  = AB_OFF + 512;                    // u16 [64][256]
constexpr size_t W1L_OFF  = W1H_OFF + (size_t)64 * 256 * 2;
constexpr size_t W2H_OFF  = W1L_OFF + (size_t)64 * 256 * 2;  // u16 [16][64][64]
constexpr size_t W2L_OFF  = W2H_OFF + (size_t)16 * 64 * 64 * 2;
constexpr size_t WS_NEED  = W2L_OFF + (size_t)16 * 64 * 64 * 2;
} // namespace

using f32x4  = __attribute__((ext_vector_type(4))) float;
using bf16x8 = __attribute__((ext_vector_type(8))) short;   // 8 bf16 = 4 VGPR

__device__ __forceinline__ unsigned short f2bf(float f) {   // RNE fp32->bf16
    unsigned u = __float_as_uint(f);
    return (unsigned short)((u + 0x7fffu + ((u >> 16) & 1u)) >> 16);
}
__device__ __forceinline__ float bf2f(unsigned short h) {
    return __uint_as_float(((unsigned)h) << 16);
}
__device__ __forceinline__ void split2(float v, unsigned short& h, unsigned short& l) {
    h = f2bf(v);
    l = f2bf(v - bf2f(h));
}
__device__ __forceinline__ f32x4 MFMA(bf16x8 a, bf16x8 b, f32x4 c) {
    return __builtin_amdgcn_mfma_f32_16x16x32_bf16(a, b, c, 0, 0, 0);
}

// ---------------------------------------------------------------------------
// K0: weight prep. w1b[o][c] = split(w1[o][c]) (already B-layout: B[k=c][n=o]
// needs 8 consecutive c per o). w2b[g][tap][cr], taps 49..63 zeroed.
// ---------------------------------------------------------------------------
__global__ __launch_bounds__(256) void k0_prep(
    const float* __restrict__ w1, const float* __restrict__ w2,
    unsigned short* __restrict__ w1h, unsigned short* __restrict__ w1l,
    unsigned short* __restrict__ w2h, unsigned short* __restrict__ w2l)
{
    const int i = blockIdx.x * 256 + threadIdx.x;
    if (i < 64 * 256) {
        unsigned short h, l;
        split2(w1[i], h, l);
        w1h[i] = h; w1l[i] = l;
    }
    const int j = i - 64 * 256;
    if (j >= 0 && j < 16 * 64 * 64) {
        const int cr = j & 63, tap = (j >> 6) & 63, g = j >> 12;
        const float v = (tap < 49) ? w2[(size_t)(tap * Gn + g) * CRn + cr] : 0.f;
        unsigned short h, l;
        split2(v, h, l);
        w2h[j] = h; w2l[j] = l;
    }
}

// ---------------------------------------------------------------------------
// K1: rT[px][o] = sum_c x[px][c] * w1[o][c], MFMA. Block = 128 px x 64 o,
// K=256 in 4 chunks of 64. x staged transposed+split into swizzled LDS.
// Also per-block BN partials (sum/sumsq per o).
// ---------------------------------------------------------------------------
__global__ __launch_bounds__(256) void k1_reduce(
    const float* __restrict__ x,
    const unsigned short* __restrict__ w1h, const unsigned short* __restrict__ w1l,
    float* __restrict__ rT, float* __restrict__ part)
{
    __shared__ unsigned xsh[128][36];   // c-pairs packed: lo16=c even, hi16=odd
    __shared__ unsigned xsl[128][36];   // stride 36 dwords: b128-alignable
    __shared__ float wps[4][64], wpq[4][64];

    const int t = threadIdx.x;
    const int wv = t >> 6, l = t & 63, lm = l & 15, lq = l >> 4;
    const int px0 = blockIdx.x * 128;

    f32x4 acc[2][4];
    #pragma unroll
    for (int m = 0; m < 2; ++m)
        #pragma unroll
        for (int n = 0; n < 4; ++n) acc[m][n] = f32x4{0.f, 0.f, 0.f, 0.f};

    for (int kc = 0; kc < 4; ++kc) {
        __syncthreads();
        // stage 64c x 128px as bf16-split pairs; XOR-swizzle kills the
        // stride-36 (4 mod 32) bank pattern on both writes and reads
        #pragma unroll 4
        for (int it = 0; it < 16; ++it) {
            const int e = it * 256 + t;         // pair-slot in [0,4096)
            const int pxl = e & 127, cp = e >> 7;
            const int px = px0 + pxl;
            const int b = px / HWn, hw = px - b * HWn;
            const float* xp = x + ((size_t)b * Cn + kc * 64 + cp * 2) * HWn + hw;
            const float v0 = xp[0], v1 = xp[HWn];
            unsigned short h0, l0, h1, l1;
            split2(v0, h0, l0);
            split2(v1, h1, l1);
            const int col = cp ^ ((pxl & 7) << 2);
            xsh[pxl][col] = (unsigned)h0 | ((unsigned)h1 << 16);
            xsl[pxl][col] = (unsigned)l0 | ((unsigned)l1 << 16);
        }
        __syncthreads();

        #pragma unroll
        for (int ks = 0; ks < 2; ++ks) {
            bf16x8 ah[2], al[2];
            #pragma unroll
            for (int m = 0; m < 2; ++m) {
                const int pxl = (wv * 2 + m) * 16 + lm;
                const int base = (ks * 16 + lq * 4) ^ ((pxl & 7) << 2);
                ah[m] = *(const bf16x8*)&xsh[pxl][base];
                al[m] = *(const bf16x8*)&xsl[pxl][base];
            }
            #pragma unroll
            for (int n = 0; n < 4; ++n) {
                const size_t wo = (size_t)(n * 16 + lm) * 256 + kc * 64 + ks * 32 + lq * 8;
                const bf16x8 bh = *(const bf16x8*)(w1h + wo);
                const bf16x8 bl = *(const bf16x8*)(w1l + wo);
                #pragma unroll
                for (int m = 0; m < 2; ++m) {
                    acc[m][n] = MFMA(al[m], bh, acc[m][n]);
                    acc[m][n] = MFMA(ah[m], bl, acc[m][n]);
                    acc[m][n] = MFMA(ah[m], bh, acc[m][n]);
                }
            }
        }
    }

    // store rT (D: col o = n*16+lm, row px = (wv*2+m)*16 + lq*4 + i)
    float s[4] = {0.f, 0.f, 0.f, 0.f}, q[4] = {0.f, 0.f, 0.f, 0.f};
    #pragma unroll
    for (int m = 0; m < 2; ++m)
        #pragma unroll
        for (int n = 0; n < 4; ++n)
            #pragma unroll
            for (int i = 0; i < 4; ++i) {
                const float v = acc[m][n][i];
                const int px = px0 + (wv * 2 + m) * 16 + lq * 4 + i;
                rT[(size_t)px * 64 + n * 16 + lm] = v;
                s[n] += v;
                q[n] += v * v;
            }
    #pragma unroll
    for (int n = 0; n < 4; ++n) {
        s[n] += __shfl_xor(s[n], 16, 64); s[n] += __shfl_xor(s[n], 32, 64);
        q[n] += __shfl_xor(q[n], 16, 64); q[n] += __shfl_xor(q[n], 32, 64);
        if (lq == 0) { wps[wv][n * 16 + lm] = s[n]; wpq[wv][n * 16 + lm] = q[n]; }
    }
    __syncthreads();
    if (t < 128) {
        const int ch = t >> 1;
        float v;
        if (t & 1) v = (wpq[0][ch] + wpq[1][ch]) + (wpq[2][ch] + wpq[3][ch]);
        else       v = (wps[0][ch] + wps[1][ch]) + (wps[2][ch] + wps[3][ch]);
        part[(size_t)blockIdx.x * 128 + t] = v;
    }
}

// ---------------------------------------------------------------------------
__global__ __launch_bounds__(128) void k2_stats(
    const float* __restrict__ part, const float* __restrict__ gamma,
    const float* __restrict__ beta, float* __restrict__ ab)
{
    const int t = threadIdx.x;           // t = o*2 + stat
    float s0 = 0.f, s1 = 0.f, s2 = 0.f, s3 = 0.f;
    for (int blk = 0; blk < K1B; blk += 4) {
        s0 += part[(size_t)(blk + 0) * 128 + t];
        s1 += part[(size_t)(blk + 1) * 128 + t];
        s2 += part[(size_t)(blk + 2) * 128 + t];
        s3 += part[(size_t)(blk + 3) * 128 + t];
    }
    __shared__ float L[128];
    L[t] = (s0 + s1) + (s2 + s3);
    __syncthreads();
    if (t < 64) {
        const float inv = 1.0f / (float)NPIX;
        const float mean = L[2 * t] * inv;
        const float var = L[2 * t + 1] * inv - mean * mean;
        const float A = gamma[t] * rsqrtf(var + EPSc);
        ab[t] = A;
        ab[64 + t] = beta[t] - mean * A;
    }
}

// ---------------------------------------------------------------------------
// K2b: rT fp32 [px][64] -> relu(A*v+B) -> bf16 hi/lo (packed ushort4 stores)
// ---------------------------------------------------------------------------
__global__ __launch_bounds__(256) void k2b_bnrelu(
    const float* __restrict__ rT, const float* __restrict__ ab,
    unsigned short* __restrict__ rh, unsigned short* __restrict__ rl)
{
    const int i = blockIdx.x * 256 + threadIdx.x;   // float4 idx, 802816 total
    const float4 v = reinterpret_cast<const float4*>(rT)[i];
    const int o0 = (i & 15) * 4;                    // 64 ch per px
    float f[4] = {v.x, v.y, v.z, v.w};
    ushort4 ph, pl;
    unsigned short* hh = &ph.x;
    unsigned short* ll = &pl.x;
    #pragma unroll
    for (int k = 0; k < 4; ++k) {
        const float A = ab[o0 + k], Bb = ab[64 + o0 + k];
        const float r = fmaxf(A * f[k] + Bb, 0.f);
        unsigned short h, l;
        split2(r, h, l);
        hh[k] = h; ll[k] = l;
    }
    reinterpret_cast<ushort4*>(rh)[i] = ph;
    reinterpret_cast<ushort4*>(rl)[i] = pl;
}

// ---------------------------------------------------------------------------
// K3: per (b,g, 28x4 px tile): MFMA span GEMM (A = rT split from global,
// B = w2b split from global) -> ker_s (+bias); one barrier; fp32 involution.
// blockIdx.z b-major so the 16 g-blocks of one b share rT in L2.
// ---------------------------------------------------------------------------
__global__ __launch_bounds__(256) void k3_fused(
    const float* __restrict__ x,
    const unsigned short* __restrict__ rh, const unsigned short* __restrict__ rl,
    const unsigned short* __restrict__ w2h, const unsigned short* __restrict__ w2l,
    const float* __restrict__ b2, float* __restrict__ out)
{
    __shared__ float ker_s[49][116];     // [tap][pxl], pxl = row*28+col
    __shared__ float xp_s[16][10][36];   // halo tile

    const int t = threadIdx.x;
    const int w0 = blockIdx.x * 28, h0 = blockIdx.y * 4;
    const int bz = blockIdx.z;
    const int b = bz >> 4, g = bz & 15;

    // ---- stage x halo (all threads; GEMM below doesn't touch xp_s)
    {
        const float* xg = x + (size_t)(b * Cn + g * 16) * HWn;
        for (int e = t; e < 16 * 10 * 34; e += 256) {
            const int d = e / 340;
            const int rem = e - d * 340;
            const int yy = rem / 34;
            const int xx = rem - yy * 34;
            const int hh = h0 + yy - 3, ww = w0 + xx - 3;
            float v = 0.f;
            if (hh >= 0 && hh < Hn && ww >= 0 && ww < Wn)
                v = xg[(size_t)d * HWn + hh * Wn + ww];
            xp_s[d][yy][xx] = v;
        }
    }

    // ---- span GEMM: M=112 px (7 m-tiles), N=64 taps (4 n-tiles), K=64
    {
        const int wv = t >> 6, l = t & 63, lm = l & 15, lq = l >> 4;
        f32x4 acc[2][4];
        #pragma unroll
        for (int m = 0; m < 2; ++m)
            #pragma unroll
            for (int n = 0; n < 4; ++n) acc[m][n] = f32x4{0.f, 0.f, 0.f, 0.f};

        bf16x8 ah[2][2], al[2][2];       // [m][k-half]
        #pragma unroll
        for (int m = 0; m < 2; ++m) {
            const int mt = wv * 2 + m;                   // wave3 m=1 -> phantom
            const int pxl = (mt < 7 ? mt * 16 : 0) + lm; // safe addr for phantom
            const int rA = pxl / 28, cA = pxl - rA * 28;
            const size_t px = (size_t)b * HWn + (h0 + rA) * Wn + w0 + cA;
            const size_t base = px * 64 + lq * 8;
            ah[m][0] = *(const bf16x8*)(rh + base);
            ah[m][1] = *(const bf16x8*)(rh + base + 32);
            al[m][0] = *(const bf16x8*)(rl + base);
            al[m][1] = *(const bf16x8*)(rl + base + 32);
        }
        #pragma unroll
        for (int n = 0; n < 4; ++n) {
            const size_t wo = (size_t)(g * 64 + n * 16 + lm) * 64 + lq * 8;
            const bf16x8 bh0 = *(const bf16x8*)(w2h + wo);
            const bf16x8 bh1 = *(const bf16x8*)(w2h + wo + 32);
            const bf16x8 bl0 = *(const bf16x8*)(w2l + wo);
            const bf16x8 bl1 = *(const bf16x8*)(w2l + wo + 32);
            #pragma unroll
            for (int m = 0; m < 2; ++m) {
                acc[m][n] = MFMA(al[m][0], bh0, acc[m][n]);
                acc[m][n] = MFMA(ah[m][0], bl0, acc[m][n]);
                acc[m][n] = MFMA(ah[m][0], bh0, acc[m][n]);
                acc[m][n] = MFMA(al[m][1], bh1, acc[m][n]);
                acc[m][n] = MFMA(ah[m][1], bl1, acc[m][n]);
                acc[m][n] = MFMA(ah[m][1], bh1, acc[m][n]);
            }
        }
        // D -> ker_s (+b2): col tap = n*16+lm, row pxl = mt*16 + lq*4 + i
        #pragma unroll
        for (int n = 0; n < 4; ++n) {
            const int tap = n * 16 + lm;
            if (tap < 49) {
                const float bb = b2[tap * Gn + g];
                #pragma unroll
                for (int m = 0; m < 2; ++m) {
                    const int mt = wv * 2 + m;
                    if (mt < 7) {
                        const int pxl = mt * 16 + lq * 4;
                        *(float4*)&ker_s[tap][pxl] =
                            make_float4(acc[m][n][0] + bb, acc[m][n][1] + bb,
                                        acc[m][n][2] + bb, acc[m][n][3] + bb);
                    }
                }
            }
        }
    }

    __syncthreads();   // the only barrier

    // ---- involution: thread (pq 0..27, dp 0..7) -> 4 px x 2 channels
    if (t < 224) {
        const int pq = t % 28, dp = t / 28;
        const int qy = pq / 7, qx = pq % 7;
        const int d0 = dp * 2;

        float o0[4] = {0.f, 0.f, 0.f, 0.f};
        float o1[4] = {0.f, 0.f, 0.f, 0.f};
        #pragma unroll
        for (int i = 0; i < 7; ++i) {
            float xr0[12], xr1[12];
            #pragma unroll
            for (int u = 0; u < 3; ++u) {
                *reinterpret_cast<float4*>(&xr0[u * 4]) =
                    *reinterpret_cast<const float4*>(&xp_s[d0][qy + i][qx * 4 + u * 4]);
                *reinterpret_cast<float4*>(&xr1[u * 4]) =
                    *reinterpret_cast<const float4*>(&xp_s[d0 + 1][qy + i][qx * 4 + u * 4]);
            }
            #pragma unroll
            for (int j = 0; j < 7; ++j) {
                const float4 kv = *reinterpret_cast<const float4*>(&ker_s[i * 7 + j][pq * 4]);
                const float kf[4] = {kv.x, kv.y, kv.z, kv.w};
                #pragma unroll
                for (int p = 0; p < 4; ++p) {
                    o0[p] += xr0[j + p] * kf[p];
                    o1[p] += xr1[j + p] * kf[p];
                }
            }
        }
        float* op = out + ((size_t)(b * Cn + g * 16 + d0) * Hn + h0 + qy) * Wn
                    + w0 + qx * 4;
        *reinterpret_cast<float4*>(op) = make_float4(o0[0], o0[1], o0[2], o0[3]);
        *reinterpret_cast<float4*>(op + HWn) = make_float4(o1[0], o1[1], o1[2], o1[3]);
    }
}

// ---------------------------------------------------------------------------
extern "C" void kernel_launch(void* const* d_in, const int* in_sizes, int n_in,
                              void* d_out, int out_size, void* d_ws, size_t ws_size,
                              hipStream_t stream)
{
    const float* x     = (const float*)d_in[0];
    const float* w1    = (const float*)d_in[1];
    // d_in[2] = b1: cancels exactly under training-mode BN
    const float* gamma = (const float*)d_in[3];
    const float* beta  = (const float*)d_in[4];
    const float* w2    = (const float*)d_in[5];
    const float* b2    = (const float*)d_in[6];
    float* out = (float*)d_out;
    char*  ws  = (char*)d_ws;

    if (ws_size < WS_NEED) return;   // fail loudly (output stays poisoned)

    float* rT            = (float*)(ws + RT_OFF);
    unsigned short* rh   = (unsigned short*)(ws + RH_OFF);
    unsigned short* rl   = (unsigned short*)(ws + RL_OFF);
    float* part          = (float*)(ws + PART_OFF);
    float* ab            = (float*)(ws + AB_OFF);
    unsigned short* w1h  = (unsigned short*)(ws + W1H_OFF);
    unsigned short* w1l  = (unsigned short*)(ws + W1L_OFF);
    unsigned short* w2h  = (unsigned short*)(ws + W2H_OFF);
    unsigned short* w2l  = (unsigned short*)(ws + W2L_OFF);

    k0_prep<<<(64 * 256 + 16 * 64 * 64) / 256, 256, 0, stream>>>(
        w1, w2, w1h, w1l, w2h, w2l);
    k1_reduce<<<K1B, 256, 0, stream>>>(x, w1h, w1l, rT, part);
    k2_stats<<<1, 128, 0, stream>>>(part, gamma, beta, ab);
    k2b_bnrelu<<<(NPIX * 64 / 4) / 256, 256, 0, stream>>>(rT, ab, rh, rl);
    k3_fused<<<dim3(2, 14, 256), 256, 0, stream>>>(x, rh, rl, w2h, w2l, b2, out);
}

// Round 6
// 335.081 us; speedup vs baseline: 1.6115x; 1.1214x over previous
//
#include <hip/hip_runtime.h>
#include <hip/hip_fp16.h>

// Involution (B=16,C=256,H=W=56,K=7,G=16,CR=64).
// GEMMs on MFMA (mfma_f32_16x16x32_bf16) via split-bf16 3-term.
// R5: occupancy attack. K3 LDS 46->23KB (fp16 ker_s + fp16 halo) ->5 blocks/CU;
// b2/A-loads hoisted off the critical path. K1 784 blocks. k2 stats parallel.

namespace {
constexpr int Bn = 16, Cn = 256, Hn = 56, Wn = 56, Gn = 16, CRn = 64;
constexpr int HWn = Hn * Wn;          // 3136
constexpr int NPIX = Bn * HWn;        // 50176
constexpr int K1B = NPIX / 64;        // 784 blocks (64-px tiles)
constexpr float EPSc = 1e-5f;

// ws byte offsets (16B-aligned)
constexpr size_t RT_OFF    = 0;                                // fp32 [NPIX][64]
constexpr size_t RH_OFF    = RT_OFF + (size_t)NPIX * 64 * 4;   // u16 [NPIX][64]
constexpr size_t RL_OFF    = RH_OFF + (size_t)NPIX * 64 * 2;
constexpr size_t PART_OFF  = RL_OFF + (size_t)NPIX * 64 * 2;   // fp32 [784][128]
constexpr size_t PART2_OFF = PART_OFF + (size_t)K1B * 128 * 4; // fp32 [16][128]
constexpr size_t AB_OFF    = PART2_OFF + 16 * 128 * 4;         // fp32 [128]
constexpr size_t W1H_OFF   = AB_OFF + 512;                     // u16 [64][256]
constexpr size_t W1L_OFF   = W1H_OFF + (size_t)64 * 256 * 2;
constexpr size_t W2H_OFF   = W1L_OFF + (size_t)64 * 256 * 2;   // u16 [16][64][64]
constexpr size_t W2L_OFF   = W2H_OFF + (size_t)16 * 64 * 64 * 2;
constexpr size_t WS_NEED   = W2L_OFF + (size_t)16 * 64 * 64 * 2;
} // namespace

using f32x4  = __attribute__((ext_vector_type(4))) float;
using bf16x8 = __attribute__((ext_vector_type(8))) short;   // 8 bf16 = 4 VGPR

__device__ __forceinline__ unsigned short f2bf(float f) {   // RNE fp32->bf16
    unsigned u = __float_as_uint(f);
    return (unsigned short)((u + 0x7fffu + ((u >> 16) & 1u)) >> 16);
}
__device__ __forceinline__ float bf2f(unsigned short h) {
    return __uint_as_float(((unsigned)h) << 16);
}
__device__ __forceinline__ void split2(float v, unsigned short& h, unsigned short& l) {
    h = f2bf(v);
    l = f2bf(v - bf2f(h));
}
__device__ __forceinline__ unsigned short f2h(float f) {
    __half h = __float2half(f);
    return *reinterpret_cast<unsigned short*>(&h);
}
__device__ __forceinline__ float h2f(unsigned short u) {
    __half h = *reinterpret_cast<__half*>(&u);
    return __half2float(h);
}
__device__ __forceinline__ f32x4 MFMA(bf16x8 a, bf16x8 b, f32x4 c) {
    return __builtin_amdgcn_mfma_f32_16x16x32_bf16(a, b, c, 0, 0, 0);
}

// ---------------------------------------------------------------------------
// K0: weight prep. w1b[o][c] bf16 hi/lo (B-operand natural layout).
// w2b[g][tap][cr] bf16 hi/lo, taps 49..63 zeroed.
// ---------------------------------------------------------------------------
__global__ __launch_bounds__(256) void k0_prep(
    const float* __restrict__ w1, const float* __restrict__ w2,
    unsigned short* __restrict__ w1h, unsigned short* __restrict__ w1l,
    unsigned short* __restrict__ w2h, unsigned short* __restrict__ w2l)
{
    const int i = blockIdx.x * 256 + threadIdx.x;
    if (i < 64 * 256) {
        unsigned short h, l;
        split2(w1[i], h, l);
        w1h[i] = h; w1l[i] = l;
    }
    const int j = i - 64 * 256;
    if (j >= 0 && j < 16 * 64 * 64) {
        const int cr = j & 63, tap = (j >> 6) & 63, g = j >> 12;
        const float v = (tap < 49) ? w2[(size_t)(tap * Gn + g) * CRn + cr] : 0.f;
        unsigned short h, l;
        split2(v, h, l);
        w2h[j] = h; w2l[j] = l;
    }
}

// ---------------------------------------------------------------------------
// K1: rT[px][o] = sum_c x[px][c]*w1[o][c], MFMA. Block = 64 px x 64 o (one
// 16-px m-tile per wave), K=256 in 4 chunks. x transposed+split into
// XOR-swizzled LDS. Emits per-block BN partials.
// ---------------------------------------------------------------------------
__global__ __launch_bounds__(256) void k1_reduce(
    const float* __restrict__ x,
    const unsigned short* __restrict__ w1h, const unsigned short* __restrict__ w1l,
    float* __restrict__ rT, float* __restrict__ part)
{
    __shared__ unsigned xsh[64][36];    // c-pairs packed: lo16=c even, hi16=odd
    __shared__ unsigned xsl[64][36];
    __shared__ float wps[4][64], wpq[4][64];

    const int t = threadIdx.x;
    const int wv = t >> 6, l = t & 63, lm = l & 15, lq = l >> 4;
    const int px0 = blockIdx.x * 64;

    f32x4 acc[4];
    #pragma unroll
    for (int n = 0; n < 4; ++n) acc[n] = f32x4{0.f, 0.f, 0.f, 0.f};

    for (int kc = 0; kc < 4; ++kc) {
        __syncthreads();
        // stage 64c x 64px as bf16-split pairs (2048 pair-slots)
        #pragma unroll
        for (int it = 0; it < 8; ++it) {
            const int e = it * 256 + t;
            const int pxl = e & 63, cp = e >> 6;
            const int px = px0 + pxl;
            const int b = px / HWn, hw = px - b * HWn;
            const float* xp = x + ((size_t)b * Cn + kc * 64 + cp * 2) * HWn + hw;
            const float v0 = xp[0], v1 = xp[HWn];
            unsigned short h0, l0, h1, l1;
            split2(v0, h0, l0);
            split2(v1, h1, l1);
            const int col = cp ^ ((pxl & 7) << 2);
            xsh[pxl][col] = (unsigned)h0 | ((unsigned)h1 << 16);
            xsl[pxl][col] = (unsigned)l0 | ((unsigned)l1 << 16);
        }
        __syncthreads();

        #pragma unroll
        for (int ks = 0; ks < 2; ++ks) {
            const int pxl = wv * 16 + lm;
            const int base = (ks * 16 + lq * 4) ^ ((pxl & 7) << 2);
            const bf16x8 ah = *(const bf16x8*)&xsh[pxl][base];
            const bf16x8 al = *(const bf16x8*)&xsl[pxl][base];
            #pragma unroll
            for (int n = 0; n < 4; ++n) {
                const size_t wo = (size_t)(n * 16 + lm) * 256 + kc * 64 + ks * 32 + lq * 8;
                const bf16x8 bh = *(const bf16x8*)(w1h + wo);
                const bf16x8 bl = *(const bf16x8*)(w1l + wo);
                acc[n] = MFMA(al, bh, acc[n]);
                acc[n] = MFMA(ah, bl, acc[n]);
                acc[n] = MFMA(ah, bh, acc[n]);
            }
        }
    }

    // store rT (D: col o = n*16+lm, row px = wv*16 + lq*4 + i)
    float s[4] = {0.f, 0.f, 0.f, 0.f}, q[4] = {0.f, 0.f, 0.f, 0.f};
    #pragma unroll
    for (int n = 0; n < 4; ++n)
        #pragma unroll
        for (int i = 0; i < 4; ++i) {
            const float v = acc[n][i];
            const int px = px0 + wv * 16 + lq * 4 + i;
            rT[(size_t)px * 64 + n * 16 + lm] = v;
            s[n] += v;
            q[n] += v * v;
        }
    #pragma unroll
    for (int n = 0; n < 4; ++n) {
        s[n] += __shfl_xor(s[n], 16, 64); s[n] += __shfl_xor(s[n], 32, 64);
        q[n] += __shfl_xor(q[n], 16, 64); q[n] += __shfl_xor(q[n], 32, 64);
        if (lq == 0) { wps[wv][n * 16 + lm] = s[n]; wpq[wv][n * 16 + lm] = q[n]; }
    }
    __syncthreads();
    if (t < 128) {
        const int ch = t >> 1;
        float v;
        if (t & 1) v = (wpq[0][ch] + wpq[1][ch]) + (wpq[2][ch] + wpq[3][ch]);
        else       v = (wps[0][ch] + wps[1][ch]) + (wps[2][ch] + wps[3][ch]);
        part[(size_t)blockIdx.x * 128 + t] = v;
    }
}

// ---------------------------------------------------------------------------
// k2a: 16 blocks x 128 thr: partial fold of 784 block-rows -> part2[16][128]
// ---------------------------------------------------------------------------
__global__ __launch_bounds__(128) void k2a_fold(
    const float* __restrict__ part, float* __restrict__ part2)
{
    const int t = threadIdx.x, j = blockIdx.x;
    float s = 0.f;
    for (int c = 0; c < K1B / 16; ++c)
        s += part[(size_t)(j * (K1B / 16) + c) * 128 + t];
    part2[(size_t)j * 128 + t] = s;
}

// ---------------------------------------------------------------------------
// k2: final fold -> per-channel BN scale A / shift B
// ---------------------------------------------------------------------------
__global__ __launch_bounds__(128) void k2_stats(
    const float* __restrict__ part2, const float* __restrict__ gamma,
    const float* __restrict__ beta, float* __restrict__ ab)
{
    const int t = threadIdx.x;           // t = o*2 + stat
    float s = 0.f;
    #pragma unroll
    for (int j = 0; j < 16; ++j) s += part2[(size_t)j * 128 + t];
    __shared__ float L[128];
    L[t] = s;
    __syncthreads();
    if (t < 64) {
        const float inv = 1.0f / (float)NPIX;
        const float mean = L[2 * t] * inv;
        const float var = L[2 * t + 1] * inv - mean * mean;
        const float A = gamma[t] * rsqrtf(var + EPSc);
        ab[t] = A;
        ab[64 + t] = beta[t] - mean * A;
    }
}

// ---------------------------------------------------------------------------
// K2b: rT fp32 [px][64] -> relu(A*v+B) -> bf16 hi/lo
// ---------------------------------------------------------------------------
__global__ __launch_bounds__(256) void k2b_bnrelu(
    const float* __restrict__ rT, const float* __restrict__ ab,
    unsigned short* __restrict__ rh, unsigned short* __restrict__ rl)
{
    const int i = blockIdx.x * 256 + threadIdx.x;   // float4 idx, 802816 total
    const float4 v = reinterpret_cast<const float4*>(rT)[i];
    const int o0 = (i & 15) * 4;
    float f[4] = {v.x, v.y, v.z, v.w};
    ushort4 ph, pl;
    unsigned short* hh = &ph.x;
    unsigned short* ll = &pl.x;
    #pragma unroll
    for (int k = 0; k < 4; ++k) {
        const float A = ab[o0 + k], Bb = ab[64 + o0 + k];
        const float r = fmaxf(A * f[k] + Bb, 0.f);
        unsigned short h, l;
        split2(r, h, l);
        hh[k] = h; ll[k] = l;
    }
    reinterpret_cast<ushort4*>(rh)[i] = ph;
    reinterpret_cast<ushort4*>(rl)[i] = pl;
}

// ---------------------------------------------------------------------------
// K3: per (b,g, 28x4 px tile): MFMA span GEMM -> ker_s (fp16); one barrier;
// fp32-accumulate involution from fp16 halo + fp16 ker. LDS ~23KB.
// ---------------------------------------------------------------------------
__global__ __launch_bounds__(256, 5) void k3_fused(
    const float* __restrict__ x,
    const unsigned short* __restrict__ rh, const unsigned short* __restrict__ rl,
    const unsigned short* __restrict__ w2h, const unsigned short* __restrict__ w2l,
    const float* __restrict__ b2, float* __restrict__ out)
{
    __shared__ unsigned short ker_h[49][116];   // [tap][pxl] fp16, 11.1 KB
    __shared__ unsigned short xp_h[16][10][36]; // [d][yy][xx] fp16, 11.5 KB

    const int t = threadIdx.x;
    const int w0 = blockIdx.x * 28, h0 = blockIdx.y * 4;
    const int bz = blockIdx.z;
    const int b = bz >> 4, g = bz & 15;
    const int wv = t >> 6, l = t & 63, lm = l & 15, lq = l >> 4;

    // ---- b2 for this thread's 4 taps (off critical path)
    float b2g[4];
    #pragma unroll
    for (int n = 0; n < 4; ++n) {
        const int tap = n * 16 + lm;
        b2g[n] = (tap < 49) ? b2[tap * Gn + g] : 0.f;
    }

    // ---- A-fragments issued early: latency hides under halo staging
    bf16x8 ah[2][2], al[2][2];       // [m][k-half]
    #pragma unroll
    for (int m = 0; m < 2; ++m) {
        const int mt = wv * 2 + m;                   // wave3 m=1 -> phantom
        const int pxl = (mt < 7 ? mt * 16 : 0) + lm;
        const int rA = pxl / 28, cA = pxl - rA * 28;
        const size_t px = (size_t)b * HWn + (h0 + rA) * Wn + w0 + cA;
        const size_t base = px * 64 + lq * 8;
        ah[m][0] = *(const bf16x8*)(rh + base);
        ah[m][1] = *(const bf16x8*)(rh + base + 32);
        al[m][0] = *(const bf16x8*)(rl + base);
        al[m][1] = *(const bf16x8*)(rl + base + 32);
    }

    // ---- stage x halo as fp16
    {
        const float* xg = x + (size_t)(b * Cn + g * 16) * HWn;
        for (int e = t; e < 16 * 10 * 34; e += 256) {
            const int d = e / 340;
            const int rem = e - d * 340;
            const int yy = rem / 34;
            const int xx = rem - yy * 34;
            const int hh = h0 + yy - 3, ww = w0 + xx - 3;
            float v = 0.f;
            if (hh >= 0 && hh < Hn && ww >= 0 && ww < Wn)
                v = xg[(size_t)d * HWn + hh * Wn + ww];
            xp_h[d][yy][xx] = f2h(v);
        }
    }

    // ---- span GEMM: M=112 px (7 m-tiles), N=64 taps, K=64
    {
        f32x4 acc[2][4];
        #pragma unroll
        for (int m = 0; m < 2; ++m)
            #pragma unroll
            for (int n = 0; n < 4; ++n) acc[m][n] = f32x4{0.f, 0.f, 0.f, 0.f};

        #pragma unroll
        for (int n = 0; n < 4; ++n) {
            const size_t wo = (size_t)(g * 64 + n * 16 + lm) * 64 + lq * 8;
            const bf16x8 bh0 = *(const bf16x8*)(w2h + wo);
            const bf16x8 bh1 = *(const bf16x8*)(w2h + wo + 32);
            const bf16x8 bl0 = *(const bf16x8*)(w2l + wo);
            const bf16x8 bl1 = *(const bf16x8*)(w2l + wo + 32);
            #pragma unroll
            for (int m = 0; m < 2; ++m) {
                acc[m][n] = MFMA(al[m][0], bh0, acc[m][n]);
                acc[m][n] = MFMA(ah[m][0], bl0, acc[m][n]);
                acc[m][n] = MFMA(ah[m][0], bh0, acc[m][n]);
                acc[m][n] = MFMA(al[m][1], bh1, acc[m][n]);
                acc[m][n] = MFMA(ah[m][1], bl1, acc[m][n]);
                acc[m][n] = MFMA(ah[m][1], bh1, acc[m][n]);
            }
        }
        // D -> ker_h (+b2): col tap = n*16+lm, row pxl = mt*16 + lq*4 + i
        #pragma unroll
        for (int n = 0; n < 4; ++n) {
            const int tap = n * 16 + lm;
            if (tap < 49) {
                const float bb = b2g[n];
                #pragma unroll
                for (int m = 0; m < 2; ++m) {
                    const int mt = wv * 2 + m;
                    if (mt < 7) {
                        const int pxl = mt * 16 + lq * 4;
                        ushort4 kv;
                        kv.x = f2h(acc[m][n][0] + bb);
                        kv.y = f2h(acc[m][n][1] + bb);
                        kv.z = f2h(acc[m][n][2] + bb);
                        kv.w = f2h(acc[m][n][3] + bb);
                        *(ushort4*)&ker_h[tap][pxl] = kv;
                    }
                }
            }
        }
    }

    __syncthreads();   // the only barrier

    // ---- involution: thread (pq 0..27, dp 0..7) -> 4 px x 2 channels
    if (t < 224) {
        const int pq = t % 28, dp = t / 28;
        const int qy = pq / 7, qx = pq % 7;
        const int d0 = dp * 2;

        float o0[4] = {0.f, 0.f, 0.f, 0.f};
        float o1[4] = {0.f, 0.f, 0.f, 0.f};
        #pragma unroll
        for (int i = 0; i < 7; ++i) {
            float xr0[12], xr1[12];
            #pragma unroll
            for (int u = 0; u < 3; ++u) {
                const ushort4 a0 = *(const ushort4*)&xp_h[d0][qy + i][qx * 4 + u * 4];
                const ushort4 a1 = *(const ushort4*)&xp_h[d0 + 1][qy + i][qx * 4 + u * 4];
                xr0[u * 4 + 0] = h2f(a0.x); xr0[u * 4 + 1] = h2f(a0.y);
                xr0[u * 4 + 2] = h2f(a0.z); xr0[u * 4 + 3] = h2f(a0.w);
                xr1[u * 4 + 0] = h2f(a1.x); xr1[u * 4 + 1] = h2f(a1.y);
                xr1[u * 4 + 2] = h2f(a1.z); xr1[u * 4 + 3] = h2f(a1.w);
            }
            #pragma unroll
            for (int j = 0; j < 7; ++j) {
                const ushort4 kq = *(const ushort4*)&ker_h[i * 7 + j][pq * 4];
                const float kf[4] = {h2f(kq.x), h2f(kq.y), h2f(kq.z), h2f(kq.w)};
                #pragma unroll
                for (int p = 0; p < 4; ++p) {
                    o0[p] += xr0[j + p] * kf[p];
                    o1[p] += xr1[j + p] * kf[p];
                }
            }
        }
        float* op = out + ((size_t)(b * Cn + g * 16 + d0) * Hn + h0 + qy) * Wn
                    + w0 + qx * 4;
        *reinterpret_cast<float4*>(op) = make_float4(o0[0], o0[1], o0[2], o0[3]);
        *reinterpret_cast<float4*>(op + HWn) = make_float4(o1[0], o1[1], o1[2], o1[3]);
    }
}

// ---------------------------------------------------------------------------
extern "C" void kernel_launch(void* const* d_in, const int* in_sizes, int n_in,
                              void* d_out, int out_size, void* d_ws, size_t ws_size,
                              hipStream_t stream)
{
    const float* x     = (const float*)d_in[0];
    const float* w1    = (const float*)d_in[1];
    // d_in[2] = b1: cancels exactly under training-mode BN
    const float* gamma = (const float*)d_in[3];
    const float* beta  = (const float*)d_in[4];
    const float* w2    = (const float*)d_in[5];
    const float* b2    = (const float*)d_in[6];
    float* out = (float*)d_out;
    char*  ws  = (char*)d_ws;

    if (ws_size < WS_NEED) return;   // fail loudly (output stays poisoned)

    float* rT            = (float*)(ws + RT_OFF);
    unsigned short* rh   = (unsigned short*)(ws + RH_OFF);
    unsigned short* rl   = (unsigned short*)(ws + RL_OFF);
    float* part          = (float*)(ws + PART_OFF);
    float* part2         = (float*)(ws + PART2_OFF);
    float* ab            = (float*)(ws + AB_OFF);
    unsigned short* w1h  = (unsigned short*)(ws + W1H_OFF);
    unsigned short* w1l  = (unsigned short*)(ws + W1L_OFF);
    unsigned short* w2h  = (unsigned short*)(ws + W2H_OFF);
    unsigned short* w2l  = (unsigned short*)(ws + W2L_OFF);

    k0_prep<<<(64 * 256 + 16 * 64 * 64) / 256, 256, 0, stream>>>(
        w1, w2, w1h, w1l, w2h, w2l);
    k1_reduce<<<K1B, 256, 0, stream>>>(x, w1h, w1l, rT, part);
    k2a_fold<<<16, 128, 0, stream>>>(part, part2);
    k2_stats<<<1, 128, 0, stream>>>(part2, gamma, beta, ab);
    k2b_bnrelu<<<(NPIX * 64 / 4) / 256, 256, 0, stream>>>(rT, ab, rh, rl);
    k3_fused<<<dim3(2, 14, 256), 256, 0, stream>>>(x, rh, rl, w2h, w2l, b2, out);
}